// Round 10
// baseline (9368.300 us; speedup 1.0000x reference)
//
#include <hip/hip_runtime.h>

// liGRU on MI355X.
// Phase 1: P[64000][2048](bf16, in d_out) = x @ [Wh;Wz]^T + column sums/sumsq.
// Phase 2: persistent scan, 8 groups (4 batch rows) x 32 WGs, 4 waves/WG.
//          Packed-gate MFMA (B cols 0-7 = Uz, 8-15 = Uh; 128 VGPR fragments),
//          z meets h via shfl_xor(8), one raw s_barrier/step (r5/r9 skeleton).
//          Exchange: u64 records { tag=t+1 (hi32) | 2x bf16 h (lo32) } -- flag IS
//          the data, per-record tag verified with retry (r2-proven).
//          ROUND 10 CHANGE: dual-plane records.
//            - hrec  (agent-scope atomics): device-wide truth, r9-proven.
//            - hsh   (shadow, plain stores): plain stores are L1-write-through ->
//              land in the producer's XCD L2. Since g=blockIdx&7 + round-robin
//              dispatch co-locates a group on ONE XCD, consumers probe the shadow
//              with sc0 (SE-scope, L1-bypass) loads served by the SAME L2
//              (~300cy) instead of the LLC (~1000+cy).
//            - Safety: tags are monotone, so a stale shadow line always shows
//              tag < t -> after <=4 probe rounds we escalate to the agent-scope
//              hrec path (proven). No assumption about sc0 semantics or XCD
//              placement affects correctness -- only speed. No hang possible
//              (r4 lesson: never let progress depend on hand-written cache bits).
//          Other lessons kept: no tag indirection (r6), no LDS handshakes in the
//          K-loop (r8), no >128-VGPR fragments (r3).
//          WAR on d_out aliasing (P bf16 read vs out f32 write): P[t+1]
//          prefetches (issued step t-1) are drained by step t's post-poll
//          vmcnt(0) BEFORE any tag-(t+1) record store; a writer of out[t+1]
//          passed poll(t+1) => saw all tags>=t+1 => all P[t+1] reads completed.
//          Prologue rendezvous covers P[0..1].

#define T_STEPS 2000
#define NCOLS   2048
#define PKEEP   0.8f
#define BN_EPSF 1e-5f
#define NW      256

typedef __attribute__((ext_vector_type(8))) short bf16x8;
typedef __attribute__((ext_vector_type(4))) float f32x4;
typedef __attribute__((ext_vector_type(4))) unsigned int u32x4;

static __device__ __forceinline__ unsigned short f2bf(float f) {
  unsigned u = __builtin_bit_cast(unsigned, f);
  unsigned r = u + 0x7FFFu + ((u >> 16) & 1u);   // RNE
  return (unsigned short)(r >> 16);
}
static __device__ __forceinline__ float bf2f(unsigned short s) {
  unsigned u = ((unsigned)s) << 16;
  return __builtin_bit_cast(float, u);
}

// ---------------- K1: convert [Wh;Wz] f32 -> bf16 ----------------
__global__ void k_convw(const float* __restrict__ Wh, const float* __restrict__ Wz,
                        unsigned short* __restrict__ Wb) {
  int i = blockIdx.x * 256 + threadIdx.x;
  int e = i * 4;
  int n = e >> 9;
  int k = e & 511;
  const float* src = (n < 1024) ? (Wh + (size_t)n * 512 + k)
                                : (Wz + (size_t)(n - 1024) * 512 + k);
  float4 v = *(const float4*)src;
  *(ushort4*)(Wb + e) = make_ushort4(f2bf(v.x), f2bf(v.y), f2bf(v.z), f2bf(v.w));
}

// ---------------- K2: GEMM  P = x @ Wb^T  (+ BN stats) ----------------
__global__ __launch_bounds__(256, 2) void k_gemm(
    const float* __restrict__ X, const unsigned short* __restrict__ Wb,
    unsigned short* __restrict__ P, float* __restrict__ sums, float* __restrict__ sumsq) {
  __shared__ __align__(16) unsigned short As[128 * 32];
  __shared__ __align__(16) unsigned short Bs[128 * 32];
  const int tid  = threadIdx.x;
  const int bm   = blockIdx.x >> 4, bn = blockIdx.x & 15;
  const int lane = tid & 63, wid = tid >> 6;
  const int wm   = wid >> 1, wn = wid & 1;
  const int lrow = lane & 15, lk = lane >> 4;

  f32x4 acc[4][4] = {};

  for (int kk = 0; kk < 512; kk += 32) {
    __syncthreads();
#pragma unroll
    for (int j = 0; j < 2; ++j) {
      int c = j * 256 + wid * 64 + lane;
      int brow = c >> 2, b8 = (c & 3) * 8;
      const unsigned short* gp = Wb + (size_t)(bn * 128 + brow) * 512 + kk + b8;
      __builtin_amdgcn_global_load_lds(
          (const __attribute__((address_space(1))) unsigned int*)gp,
          (__attribute__((address_space(3))) unsigned int*)(Bs + (size_t)(j * 256 + wid * 64) * 8),
          16, 0, 0);
    }
    {
      int arow = tid >> 1, ahalf = tid & 1;
      const float4* xp = (const float4*)(X + (size_t)(bm * 128 + arow) * 512 + kk + ahalf * 16);
      unsigned v[8];
#pragma unroll
      for (int j = 0; j < 4; ++j) {
        float4 f = xp[j];
        v[j * 2 + 0] = (unsigned)f2bf(f.x) | ((unsigned)f2bf(f.y) << 16);
        v[j * 2 + 1] = (unsigned)f2bf(f.z) | ((unsigned)f2bf(f.w) << 16);
      }
      u32x4* ap = (u32x4*)(As + arow * 32 + ahalf * 16);
      u32x4 t0 = {v[0], v[1], v[2], v[3]};
      u32x4 t1 = {v[4], v[5], v[6], v[7]};
      ap[0] = t0; ap[1] = t1;
    }
    __syncthreads();

    bf16x8 af[4], bfr[4];
#pragma unroll
    for (int mt = 0; mt < 4; ++mt)
      af[mt] = *(const bf16x8*)(As + (wm * 64 + mt * 16 + lrow) * 32 + lk * 8);
#pragma unroll
    for (int nt = 0; nt < 4; ++nt)
      bfr[nt] = *(const bf16x8*)(Bs + (wn * 64 + nt * 16 + lrow) * 32 + lk * 8);
#pragma unroll
    for (int mt = 0; mt < 4; ++mt)
#pragma unroll
      for (int nt = 0; nt < 4; ++nt)
        acc[mt][nt] = __builtin_amdgcn_mfma_f32_16x16x32_bf16(af[mt], bfr[nt], acc[mt][nt], 0, 0, 0);
  }

#pragma unroll
  for (int mt = 0; mt < 4; ++mt)
#pragma unroll
    for (int nt = 0; nt < 4; ++nt) {
      f32x4 a = acc[mt][nt];
      int gcol  = bn * 128 + wn * 64 + nt * 16 + lrow;
      int grow0 = bm * 128 + wm * 64 + mt * 16 + lk * 4;
#pragma unroll
      for (int rr = 0; rr < 4; ++rr)
        P[(size_t)(grow0 + rr) * NCOLS + gcol] = f2bf(a[rr]);
    }
#pragma unroll
  for (int nt = 0; nt < 4; ++nt) {
    float s = 0.f, q = 0.f;
#pragma unroll
    for (int mt = 0; mt < 4; ++mt) {
      f32x4 a = acc[mt][nt];
#pragma unroll
      for (int rr = 0; rr < 4; ++rr) { s += a[rr]; q += a[rr] * a[rr]; }
    }
    s += __shfl_xor(s, 16); s += __shfl_xor(s, 32);
    q += __shfl_xor(q, 16); q += __shfl_xor(q, 32);
    if (lane < 16) {
      int gcol = bn * 128 + wn * 64 + nt * 16 + lrow;
      atomicAdd(&sums[gcol], s);
      atomicAdd(&sumsq[gcol], q);
    }
  }
}

// ---------------- K3: persistent scan ----------------
__global__ __launch_bounds__(256, 1) void k_scan(
    const float* __restrict__ Uh, const float* __restrict__ Uz,
    const float* __restrict__ gwh, const float* __restrict__ bwh,
    const float* __restrict__ gwz, const float* __restrict__ bwz,
    const unsigned short* P,            // aliases d_out (bf16 view) -- no restrict!
    const float* __restrict__ sums, const float* __restrict__ sumsq,
    unsigned long long* hrec,           // [8][2][2048] u64 records (agent truth)
    unsigned long long* hsh,            // [8][2][2048] u64 shadow (L2 fast path)
    unsigned int* ctrl,                 // [0]=rendezvous counter
    float* out)                         // aliases d_out (f32 view) -- no restrict!
{
  // hlds double-buffered by step parity: [2][4 rows][1024 units] bf16, XOR-swizzled
  __shared__ __align__(16) unsigned char hlds[16384];

  const int tid  = threadIdx.x;
  const int lane = tid & 63;
  const int wid  = tid >> 6;
  const int lrow = lane & 15, lk = lane >> 4;

  const int g    = blockIdx.x & 7;       // group = 4 batch rows (co-XCD by round-robin)
  const int role = blockIdx.x >> 3;      // [0,32): unit block
  const int b0   = g * 4;
  const int u0w  = role * 32 + wid * 8;  // this wave's 8 units
  const bool isH = (lrow >= 8);          // B col 0-7 = z, 8-15 = h
  const int unit = u0w + (lrow & 7);
  const int col  = isH ? unit : (1024 + unit);   // P column for this lane's gate

  // ---- BatchNorm scale/bias for this lane's column ----
  float scl, bia;
  {
    float s = sums[col], q = sumsq[col];
    float gam = isH ? gwh[unit] : gwz[unit];
    float bet = isH ? bwh[unit] : bwz[unit];
    float mean = s * (1.0f / 64000.0f);
    float var  = q * (1.0f / 64000.0f) - mean * mean;
    float rstd = rsqrtf(var + BN_EPSF);
    scl = gam * rstd;
    bia = bet - mean * scl;
  }

  // ---- preload this lane's U row (x PKEEP) as 32 MFMA B-fragments (128 VGPRs)
  const float* urow = (isH ? Uh : Uz) + (size_t)unit * 1024;
  bf16x8 bfrag[32];
#pragma unroll
  for (int kt = 0; kt < 32; ++kt) {
    const float4* p4 = (const float4*)(urow + kt * 32 + lk * 8);
    float4 fa = p4[0], fb = p4[1];
    bf16x8 tv;
    tv[0] = (short)f2bf(fa.x * PKEEP); tv[1] = (short)f2bf(fa.y * PKEEP);
    tv[2] = (short)f2bf(fa.z * PKEEP); tv[3] = (short)f2bf(fa.w * PKEEP);
    tv[4] = (short)f2bf(fb.x * PKEEP); tv[5] = (short)f2bf(fb.y * PKEEP);
    tv[6] = (short)f2bf(fb.z * PKEEP); tv[7] = (short)f2bf(fb.w * PKEEP);
    bfrag[kt] = tv;
  }

  // ---- P prefetch prologue: pf=P[0], pn1=P[1] ----
  unsigned short pf[4], pn1[4];
#pragma unroll
  for (int rr = 0; rr < 4; ++rr) {
    pf[rr]  = P[(size_t)(b0 + rr) * NCOLS + col];
    pn1[rr] = P[(size_t)(32 + b0 + rr) * NCOLS + col];
  }
  __syncthreads();   // full drain: my initial P loads complete

  // ---- rendezvous: ALL WGs' initial P loads drained before anyone writes out[0/1]
  if (tid == 0) {
    __hip_atomic_fetch_add(&ctrl[0], 1u, __ATOMIC_RELEASE, __HIP_MEMORY_SCOPE_AGENT);
    while (__hip_atomic_load(&ctrl[0], __ATOMIC_RELAXED, __HIP_MEMORY_SCOPE_AGENT) < NW)
      __builtin_amdgcn_s_sleep(8);
  }
  __syncthreads();

  float hown[4] = {0.f, 0.f, 0.f, 0.f};

  for (int t = 0; t < T_STEPS; ++t) {
    const int par = t & 1;

    // ---- 1. poll: fast probe of the shadow via sc0 (XCD-L2), tag-verified;
    //      escalate to agent-scope hrec (proven) after 4 stale rounds. ----
    const unsigned long long* rb = hrec + (((size_t)(g * 2 + par)) << 11) + tid;
    const unsigned long long* sb = hsh  + (((size_t)(g * 2 + par)) << 11) + tid;
    unsigned long long rec[8];
#pragma unroll
    for (int j = 0; j < 8; ++j)
      asm volatile("global_load_dwordx2 %0, %1, off sc0"
                   : "=&v"(rec[j]) : "v"(sb + 256 * j) : "memory");
    asm volatile("s_waitcnt vmcnt(0)" ::: "memory");
    __builtin_amdgcn_sched_barrier(0);
    {
      int spins = 0;
      while (true) {
        unsigned bad = 0;
#pragma unroll
        for (int j = 0; j < 8; ++j)
          if ((unsigned)(rec[j] >> 32) < (unsigned)t) bad |= (1u << j);
        if (!bad) break;
        if (spins < 4) {
          ++spins;
#pragma unroll
          for (int j = 0; j < 8; ++j)
            if (bad & (1u << j))
              asm volatile("global_load_dwordx2 %0, %1, off sc0"
                           : "=&v"(rec[j]) : "v"(sb + 256 * j) : "memory");
          asm volatile("s_waitcnt vmcnt(0)" ::: "memory");
          __builtin_amdgcn_sched_barrier(0);
        } else {
          __builtin_amdgcn_s_sleep(1);
#pragma unroll
          for (int j = 0; j < 8; ++j)
            if (bad & (1u << j))
              rec[j] = __hip_atomic_load(rb + 256 * j, __ATOMIC_RELAXED,
                                         __HIP_MEMORY_SCOPE_AGENT);
        }
      }
    }
    // full vmem drain: P[t+1] (issued last step) completed -> WAR proof for tag t+1
    asm volatile("s_waitcnt vmcnt(0)" ::: "memory");

    // ---- 2. prefetch P[t+2]: rides across barrier + all stores until next poll
    unsigned short pn2[4] = {0, 0, 0, 0};
    if (t + 2 < T_STEPS) {
#pragma unroll
      for (int rr = 0; rr < 4; ++rr)
        pn2[rr] = P[(size_t)((t + 2) * 32 + b0 + rr) * NCOLS + col];
    }

    // ---- 3. unpack h records into hlds[par] (XOR-swizzled) ----
    unsigned char* hb = hlds + par * 8192;
#pragma unroll
    for (int j = 0; j < 8; ++j) {
      int idx = tid + 256 * j;
      int row = idx >> 9, up = idx & 511;
      int byteoff = (row * 2048 + up * 4) ^ ((row & 3) << 5);
      *(unsigned*)(hb + byteoff) = (unsigned)rec[j];
    }
    // single raw barrier per step: LDS-only drain; P[t+2] stays in flight
    asm volatile("s_waitcnt lgkmcnt(0)" ::: "memory");
    __builtin_amdgcn_sched_barrier(0);
    __builtin_amdgcn_s_barrier();
    __builtin_amdgcn_sched_barrier(0);

    // ---- 4. packed dot: one MFMA stream computes BOTH gates ----
    f32x4 ac0 = {0.f, 0.f, 0.f, 0.f}, ac1 = ac0, ac2 = ac0, ac3 = ac0;
#pragma unroll
    for (int kt = 0; kt < 32; ++kt) {
      int ab = ((lane & 3) * 2048 + kt * 64 + lk * 16) ^ ((lane & 3) << 5);
      bf16x8 af = *(const bf16x8*)(hb + ab);
      if ((kt & 3) == 0)      ac0 = __builtin_amdgcn_mfma_f32_16x16x32_bf16(af, bfrag[kt], ac0, 0, 0, 0);
      else if ((kt & 3) == 1) ac1 = __builtin_amdgcn_mfma_f32_16x16x32_bf16(af, bfrag[kt], ac1, 0, 0, 0);
      else if ((kt & 3) == 2) ac2 = __builtin_amdgcn_mfma_f32_16x16x32_bf16(af, bfrag[kt], ac2, 0, 0, 0);
      else                    ac3 = __builtin_amdgcn_mfma_f32_16x16x32_bf16(af, bfrag[kt], ac3, 0, 0, 0);
    }
    f32x4 dsum = (ac0 + ac1) + (ac2 + ac3);

    // ---- 5. epilogue: z meets h via shfl_xor(8); lanes 8-15 own the update ----
    float pre[4], oth[4];
#pragma unroll
    for (int rr = 0; rr < 4; ++rr) {
      pre[rr] = dsum[rr] + bf2f(pf[rr]) * scl + bia;
      oth[rr] = __shfl_xor(pre[rr], 8);     // all lanes participate
    }

    if (lk == 0 && isH) {                    // lanes 8..15: pre=h-pre, oth=z-pre
      float hn[4];
#pragma unroll
      for (int rr = 0; rr < 4; ++rr) {
        float zz = 1.0f / (1.0f + __expf(-oth[rr]));
        float hc = fmaxf(pre[rr], 0.0f) * PKEEP;      // relu * 'orig' dropout
        hn[rr] = zz * hown[rr] + (1.0f - zz) * hc;
        hown[rr] = hn[rr];
      }
      float pp[4];
#pragma unroll
      for (int rr = 0; rr < 4; ++rr) pp[rr] = __shfl_xor(hn[rr], 1);  // 8<->9 etc
      if ((lane & 1) == 0) {                 // lanes 8,10,12,14: even units
        const size_t bofs = (((size_t)(g * 2 + ((t + 1) & 1))) << 11) + (unit >> 1);
        unsigned long long* hbn = hrec + bofs;
        unsigned long long* hsn = hsh  + bofs;
        unsigned tagw = (unsigned)(t + 1);
#pragma unroll
        for (int rr = 0; rr < 4; ++rr) {
          unsigned long long rcd = ((unsigned long long)tagw << 32)
                                 | (unsigned)f2bf(hn[rr]) | ((unsigned)f2bf(pp[rr]) << 16);
          hsn[rr * 512] = rcd;               // plain: write-through -> this XCD's L2
          __hip_atomic_store(hbn + rr * 512, rcd,
                             __ATOMIC_RELAXED, __HIP_MEMORY_SCOPE_AGENT);
        }
#pragma unroll
        for (int rr = 0; rr < 4; ++rr) {
          float2 ov = {hn[rr], pp[rr]};
          *(float2*)(out + (size_t)(t * 32 + b0 + rr) * 1024 + unit) = ov;
        }
      }
    }

#pragma unroll
    for (int rr = 0; rr < 4; ++rr) { pf[rr] = pn1[rr]; pn1[rr] = pn2[rr]; }
  }
}

// ---------------- launch ----------------
extern "C" void kernel_launch(void* const* d_in, const int* in_sizes, int n_in,
                              void* d_out, int out_size, void* d_ws, size_t ws_size,
                              hipStream_t stream) {
  (void)in_sizes; (void)n_in; (void)out_size; (void)ws_size;
  const float* x   = (const float*)d_in[0];
  const float* Wh  = (const float*)d_in[1];
  const float* Wz  = (const float*)d_in[2];
  const float* Uh  = (const float*)d_in[3];
  const float* Uz  = (const float*)d_in[4];
  const float* gwh = (const float*)d_in[5];
  const float* bwh = (const float*)d_in[6];
  const float* gwz = (const float*)d_in[7];
  const float* bwz = (const float*)d_in[8];

  char* ws = (char*)d_ws;
  float*              sums  = (float*)(ws + 0);                  // 8192 B
  float*              sumsq = (float*)(ws + 8192);               // 8192 B
  unsigned long long* hrec  = (unsigned long long*)(ws + 16384); // 262144 B
  unsigned long long* hsh   = (unsigned long long*)(ws + 278528);// 262144 B
  unsigned int*       ctrl  = (unsigned int*)(ws + 540672);      // 128 B
  unsigned short*     Wb    = (unsigned short*)(ws + 540800);    // 2 MiB

  // zero stats + both record planes + ctrl every call (graph-replay safe;
  // tag=0 == valid h0=0 in both planes)
  hipMemsetAsync(d_ws, 0, 540800, stream);
  k_convw<<<1024, 256, 0, stream>>>(Wh, Wz, Wb);
  // P (bf16) lives in d_out; scan overwrites it with f32 output in provably-ordered fashion
  k_gemm<<<8000, 256, 0, stream>>>(x, Wb, (unsigned short*)d_out, sums, sumsq);
  k_scan<<<NW, 256, 0, stream>>>(Uh, Uz, gwh, bwh, gwz, bwz,
                                 (const unsigned short*)d_out, sums, sumsq,
                                 hrec, hsh, ctrl, (float*)d_out);
}

// Round 11
// 7845.950 us; speedup vs baseline: 1.1940x; 1.1940x over previous
//
#include <hip/hip_runtime.h>

// liGRU on MI355X.
// Phase 1: P[64000][2048](bf16, in d_out) = x @ [Wh;Wz]^T + column sums/sumsq.
// Phase 2: persistent scan, 8 groups (4 batch rows) x 32 WGs, 4 waves/WG.
//          Packed-gate MFMA (B cols 0-7 = Uz, 8-15 = Uh; 128 VGPR fragments),
//          z meets h via shfl_xor(8), one raw s_barrier/step (r5/r9 skeleton).
//          Exchange: u64 records { tag=t+1 (hi32) | 2x bf16 h (lo32) }, agent
//          scope -- flag IS the data, per-record tag verified with retry.
//          ROUND 11 CHANGE (single variable vs r9): the record poll never
//          sleeps; between re-polls each wave runs a 64-deep dependent v_fma
//          filler (live via asm sink). Rationale: r9's counters imply the scan
//          executes ~2800 SIMD-cycles/step but 3.72us wall -> effective clock
//          ~750 MHz. s_sleep-heavy spinning collapses device utilization and
//          the DPM governor downclocks ~3x. Busy VALU during waits holds
//          utilization (and thus frequency) up. Zero protocol change.
//          Lessons kept: no sc0/sc1 fast paths (r4 hang, r10 stale-shadow),
//          no tag indirection (r6), no LDS handshakes in K-loop (r8),
//          no >128-VGPR fragments (r3).
//          WAR on d_out aliasing (P bf16 read vs out f32 write): P[t+1]
//          prefetches (issued step t-1) are drained by step t's post-poll
//          vmcnt(0) BEFORE any tag-(t+1) record store; a writer of out[t+1]
//          passed poll(t+1) => saw all tags>=t+1 => all P[t+1] reads completed.
//          Prologue rendezvous covers P[0..1].

#define T_STEPS 2000
#define NCOLS   2048
#define PKEEP   0.8f
#define BN_EPSF 1e-5f
#define NW      256

typedef __attribute__((ext_vector_type(8))) short bf16x8;
typedef __attribute__((ext_vector_type(4))) float f32x4;
typedef __attribute__((ext_vector_type(4))) unsigned int u32x4;

static __device__ __forceinline__ unsigned short f2bf(float f) {
  unsigned u = __builtin_bit_cast(unsigned, f);
  unsigned r = u + 0x7FFFu + ((u >> 16) & 1u);   // RNE
  return (unsigned short)(r >> 16);
}
static __device__ __forceinline__ float bf2f(unsigned short s) {
  unsigned u = ((unsigned)s) << 16;
  return __builtin_bit_cast(float, u);
}

// ---------------- K1: convert [Wh;Wz] f32 -> bf16 ----------------
__global__ void k_convw(const float* __restrict__ Wh, const float* __restrict__ Wz,
                        unsigned short* __restrict__ Wb) {
  int i = blockIdx.x * 256 + threadIdx.x;
  int e = i * 4;
  int n = e >> 9;
  int k = e & 511;
  const float* src = (n < 1024) ? (Wh + (size_t)n * 512 + k)
                                : (Wz + (size_t)(n - 1024) * 512 + k);
  float4 v = *(const float4*)src;
  *(ushort4*)(Wb + e) = make_ushort4(f2bf(v.x), f2bf(v.y), f2bf(v.z), f2bf(v.w));
}

// ---------------- K2: GEMM  P = x @ Wb^T  (+ BN stats) ----------------
__global__ __launch_bounds__(256, 2) void k_gemm(
    const float* __restrict__ X, const unsigned short* __restrict__ Wb,
    unsigned short* __restrict__ P, float* __restrict__ sums, float* __restrict__ sumsq) {
  __shared__ __align__(16) unsigned short As[128 * 32];
  __shared__ __align__(16) unsigned short Bs[128 * 32];
  const int tid  = threadIdx.x;
  const int bm   = blockIdx.x >> 4, bn = blockIdx.x & 15;
  const int lane = tid & 63, wid = tid >> 6;
  const int wm   = wid >> 1, wn = wid & 1;
  const int lrow = lane & 15, lk = lane >> 4;

  f32x4 acc[4][4] = {};

  for (int kk = 0; kk < 512; kk += 32) {
    __syncthreads();
#pragma unroll
    for (int j = 0; j < 2; ++j) {
      int c = j * 256 + wid * 64 + lane;
      int brow = c >> 2, b8 = (c & 3) * 8;
      const unsigned short* gp = Wb + (size_t)(bn * 128 + brow) * 512 + kk + b8;
      __builtin_amdgcn_global_load_lds(
          (const __attribute__((address_space(1))) unsigned int*)gp,
          (__attribute__((address_space(3))) unsigned int*)(Bs + (size_t)(j * 256 + wid * 64) * 8),
          16, 0, 0);
    }
    {
      int arow = tid >> 1, ahalf = tid & 1;
      const float4* xp = (const float4*)(X + (size_t)(bm * 128 + arow) * 512 + kk + ahalf * 16);
      unsigned v[8];
#pragma unroll
      for (int j = 0; j < 4; ++j) {
        float4 f = xp[j];
        v[j * 2 + 0] = (unsigned)f2bf(f.x) | ((unsigned)f2bf(f.y) << 16);
        v[j * 2 + 1] = (unsigned)f2bf(f.z) | ((unsigned)f2bf(f.w) << 16);
      }
      u32x4* ap = (u32x4*)(As + arow * 32 + ahalf * 16);
      u32x4 t0 = {v[0], v[1], v[2], v[3]};
      u32x4 t1 = {v[4], v[5], v[6], v[7]};
      ap[0] = t0; ap[1] = t1;
    }
    __syncthreads();

    bf16x8 af[4], bfr[4];
#pragma unroll
    for (int mt = 0; mt < 4; ++mt)
      af[mt] = *(const bf16x8*)(As + (wm * 64 + mt * 16 + lrow) * 32 + lk * 8);
#pragma unroll
    for (int nt = 0; nt < 4; ++nt)
      bfr[nt] = *(const bf16x8*)(Bs + (wn * 64 + nt * 16 + lrow) * 32 + lk * 8);
#pragma unroll
    for (int mt = 0; mt < 4; ++mt)
#pragma unroll
      for (int nt = 0; nt < 4; ++nt)
        acc[mt][nt] = __builtin_amdgcn_mfma_f32_16x16x32_bf16(af[mt], bfr[nt], acc[mt][nt], 0, 0, 0);
  }

#pragma unroll
  for (int mt = 0; mt < 4; ++mt)
#pragma unroll
    for (int nt = 0; nt < 4; ++nt) {
      f32x4 a = acc[mt][nt];
      int gcol  = bn * 128 + wn * 64 + nt * 16 + lrow;
      int grow0 = bm * 128 + wm * 64 + mt * 16 + lk * 4;
#pragma unroll
      for (int rr = 0; rr < 4; ++rr)
        P[(size_t)(grow0 + rr) * NCOLS + gcol] = f2bf(a[rr]);
    }
#pragma unroll
  for (int nt = 0; nt < 4; ++nt) {
    float s = 0.f, q = 0.f;
#pragma unroll
    for (int mt = 0; mt < 4; ++mt) {
      f32x4 a = acc[mt][nt];
#pragma unroll
      for (int rr = 0; rr < 4; ++rr) { s += a[rr]; q += a[rr] * a[rr]; }
    }
    s += __shfl_xor(s, 16); s += __shfl_xor(s, 32);
    q += __shfl_xor(q, 16); q += __shfl_xor(q, 32);
    if (lane < 16) {
      int gcol = bn * 128 + wn * 64 + nt * 16 + lrow;
      atomicAdd(&sums[gcol], s);
      atomicAdd(&sumsq[gcol], q);
    }
  }
}

// ---------------- K3: persistent scan ----------------
__global__ __launch_bounds__(256, 1) void k_scan(
    const float* __restrict__ Uh, const float* __restrict__ Uz,
    const float* __restrict__ gwh, const float* __restrict__ bwh,
    const float* __restrict__ gwz, const float* __restrict__ bwz,
    const unsigned short* P,            // aliases d_out (bf16 view) -- no restrict!
    const float* __restrict__ sums, const float* __restrict__ sumsq,
    unsigned long long* hrec,           // [8][2][2048] u64 records
    unsigned int* ctrl,                 // [0]=rendezvous counter
    float* out)                         // aliases d_out (f32 view) -- no restrict!
{
  // hlds double-buffered by step parity: [2][4 rows][1024 units] bf16, XOR-swizzled
  __shared__ __align__(16) unsigned char hlds[16384];

  const int tid  = threadIdx.x;
  const int lane = tid & 63;
  const int wid  = tid >> 6;
  const int lrow = lane & 15, lk = lane >> 4;

  const int g    = blockIdx.x & 7;       // group = 4 batch rows
  const int role = blockIdx.x >> 3;      // [0,32): unit block
  const int b0   = g * 4;
  const int u0w  = role * 32 + wid * 8;  // this wave's 8 units
  const bool isH = (lrow >= 8);          // B col 0-7 = z, 8-15 = h
  const int unit = u0w + (lrow & 7);
  const int col  = isH ? unit : (1024 + unit);   // P column for this lane's gate

  // ---- BatchNorm scale/bias for this lane's column ----
  float scl, bia;
  {
    float s = sums[col], q = sumsq[col];
    float gam = isH ? gwh[unit] : gwz[unit];
    float bet = isH ? bwh[unit] : bwz[unit];
    float mean = s * (1.0f / 64000.0f);
    float var  = q * (1.0f / 64000.0f) - mean * mean;
    float rstd = rsqrtf(var + BN_EPSF);
    scl = gam * rstd;
    bia = bet - mean * scl;
  }

  // ---- preload this lane's U row (x PKEEP) as 32 MFMA B-fragments (128 VGPRs)
  //      packed: B rows 0-7 = Uz[u0w..], rows 8-15 = Uh[u0w..]
  const float* urow = (isH ? Uh : Uz) + (size_t)unit * 1024;
  bf16x8 bfrag[32];
#pragma unroll
  for (int kt = 0; kt < 32; ++kt) {
    const float4* p4 = (const float4*)(urow + kt * 32 + lk * 8);
    float4 fa = p4[0], fb = p4[1];
    bf16x8 tv;
    tv[0] = (short)f2bf(fa.x * PKEEP); tv[1] = (short)f2bf(fa.y * PKEEP);
    tv[2] = (short)f2bf(fa.z * PKEEP); tv[3] = (short)f2bf(fa.w * PKEEP);
    tv[4] = (short)f2bf(fb.x * PKEEP); tv[5] = (short)f2bf(fb.y * PKEEP);
    tv[6] = (short)f2bf(fb.z * PKEEP); tv[7] = (short)f2bf(fb.w * PKEEP);
    bfrag[kt] = tv;
  }

  // ---- P prefetch prologue: pf=P[0], pn1=P[1] ----
  unsigned short pf[4], pn1[4];
#pragma unroll
  for (int rr = 0; rr < 4; ++rr) {
    pf[rr]  = P[(size_t)(b0 + rr) * NCOLS + col];
    pn1[rr] = P[(size_t)(32 + b0 + rr) * NCOLS + col];
  }
  __syncthreads();   // full drain: my initial P loads complete

  // ---- rendezvous: ALL WGs' initial P loads drained before anyone can write
  //      out rows 0/1 (WAR on the d_out aliasing).
  if (tid == 0) {
    __hip_atomic_fetch_add(&ctrl[0], 1u, __ATOMIC_RELEASE, __HIP_MEMORY_SCOPE_AGENT);
    while (__hip_atomic_load(&ctrl[0], __ATOMIC_RELAXED, __HIP_MEMORY_SCOPE_AGENT) < NW)
      __builtin_amdgcn_s_sleep(8);
  }
  __syncthreads();

  float hown[4] = {0.f, 0.f, 0.f, 0.f};
  float dummy = scl * 0.5f + 1.0f;   // clock-holding filler state (kept live)

  for (int t = 0; t < T_STEPS; ++t) {
    const int par = t & 1;

    // ---- 1. poll this thread's 8 records (parity par); tag carries the data.
    //      NO s_sleep: between re-polls run a dependent v_fma chain so the
    //      SIMDs stay busy and the DPM governor holds clocks up.
    const unsigned long long* rb = hrec + (((size_t)(g * 2 + par)) << 11) + tid;
    unsigned long long rec[8];
#pragma unroll
    for (int j = 0; j < 8; ++j)
      rec[j] = __hip_atomic_load(rb + 256 * j, __ATOMIC_RELAXED, __HIP_MEMORY_SCOPE_AGENT);
    while (true) {
      unsigned bad = 0;
#pragma unroll
      for (int j = 0; j < 8; ++j)
        if ((unsigned)(rec[j] >> 32) < (unsigned)t) bad |= (1u << j);
      if (!bad) break;
      // clock-holding filler: ~128 cycles of dependent VALU work
#pragma unroll
      for (int q = 0; q < 64; ++q)
        dummy = __builtin_fmaf(dummy, 1.0000001f, 1.0e-30f);
      asm volatile("" : "+v"(dummy));
#pragma unroll
      for (int j = 0; j < 8; ++j)
        if (bad & (1u << j))
          rec[j] = __hip_atomic_load(rb + 256 * j, __ATOMIC_RELAXED, __HIP_MEMORY_SCOPE_AGENT);
    }
    // full vmem drain: P[t+1] (issued last step) completed -> WAR proof for tag t+1
    asm volatile("s_waitcnt vmcnt(0)" ::: "memory");

    // ---- 2. prefetch P[t+2]: rides across barrier + all stores until next poll
    unsigned short pn2[4] = {0, 0, 0, 0};
    if (t + 2 < T_STEPS) {
#pragma unroll
      for (int rr = 0; rr < 4; ++rr)
        pn2[rr] = P[(size_t)((t + 2) * 32 + b0 + rr) * NCOLS + col];
    }

    // ---- 3. unpack h records into hlds[par] (XOR-swizzled) ----
    unsigned char* hb = hlds + par * 8192;
#pragma unroll
    for (int j = 0; j < 8; ++j) {
      int idx = tid + 256 * j;
      int row = idx >> 9, up = idx & 511;
      int byteoff = (row * 2048 + up * 4) ^ ((row & 3) << 5);
      *(unsigned*)(hb + byteoff) = (unsigned)rec[j];
    }
    // single raw barrier per step: LDS-only drain; P[t+2] stays in flight
    asm volatile("s_waitcnt lgkmcnt(0)" ::: "memory");
    __builtin_amdgcn_sched_barrier(0);
    __builtin_amdgcn_s_barrier();
    __builtin_amdgcn_sched_barrier(0);

    // ---- 4. packed dot: one MFMA stream computes BOTH gates ----
    f32x4 ac0 = {0.f, 0.f, 0.f, 0.f}, ac1 = ac0, ac2 = ac0, ac3 = ac0;
#pragma unroll
    for (int kt = 0; kt < 32; ++kt) {
      int ab = ((lane & 3) * 2048 + kt * 64 + lk * 16) ^ ((lane & 3) << 5);
      bf16x8 af = *(const bf16x8*)(hb + ab);
      if ((kt & 3) == 0)      ac0 = __builtin_amdgcn_mfma_f32_16x16x32_bf16(af, bfrag[kt], ac0, 0, 0, 0);
      else if ((kt & 3) == 1) ac1 = __builtin_amdgcn_mfma_f32_16x16x32_bf16(af, bfrag[kt], ac1, 0, 0, 0);
      else if ((kt & 3) == 2) ac2 = __builtin_amdgcn_mfma_f32_16x16x32_bf16(af, bfrag[kt], ac2, 0, 0, 0);
      else                    ac3 = __builtin_amdgcn_mfma_f32_16x16x32_bf16(af, bfrag[kt], ac3, 0, 0, 0);
    }
    f32x4 dsum = (ac0 + ac1) + (ac2 + ac3);

    // ---- 5. epilogue: z meets h via shfl_xor(8); lanes 8-15 own the update ----
    float pre[4], oth[4];
#pragma unroll
    for (int rr = 0; rr < 4; ++rr) {
      pre[rr] = dsum[rr] + bf2f(pf[rr]) * scl + bia;
      oth[rr] = __shfl_xor(pre[rr], 8);     // all lanes participate
    }

    if (lk == 0 && isH) {                    // lanes 8..15: pre=h-pre, oth=z-pre
      float hn[4];
#pragma unroll
      for (int rr = 0; rr < 4; ++rr) {
        float zz = 1.0f / (1.0f + __expf(-oth[rr]));
        float hc = fmaxf(pre[rr], 0.0f) * PKEEP;      // relu * 'orig' dropout
        hn[rr] = zz * hown[rr] + (1.0f - zz) * hc;
        hown[rr] = hn[rr];
      }
      float pp[4];
#pragma unroll
      for (int rr = 0; rr < 4; ++rr) pp[rr] = __shfl_xor(hn[rr], 1);  // 8<->9 etc
      if ((lane & 1) == 0) {                 // lanes 8,10,12,14: even units
        unsigned long long* hbn = hrec + (((size_t)(g * 2 + ((t + 1) & 1))) << 11)
                                + (unit >> 1);
        unsigned tagw = (unsigned)(t + 1);
#pragma unroll
        for (int rr = 0; rr < 4; ++rr) {
          unsigned long long rcd = ((unsigned long long)tagw << 32)
                                 | (unsigned)f2bf(hn[rr]) | ((unsigned)f2bf(pp[rr]) << 16);
          __hip_atomic_store(hbn + rr * 512, rcd,
                             __ATOMIC_RELAXED, __HIP_MEMORY_SCOPE_AGENT);
        }
#pragma unroll
        for (int rr = 0; rr < 4; ++rr) {
          float2 ov = {hn[rr], pp[rr]};
          *(float2*)(out + (size_t)(t * 32 + b0 + rr) * 1024 + unit) = ov;
        }
      }
    }

#pragma unroll
    for (int rr = 0; rr < 4; ++rr) { pf[rr] = pn1[rr]; pn1[rr] = pn2[rr]; }
  }
  // keep the filler state observable so it is never DCE'd
  if (dummy == 1.0e30f && tid == 0) ctrl[64] = 1u;
}

// ---------------- launch ----------------
extern "C" void kernel_launch(void* const* d_in, const int* in_sizes, int n_in,
                              void* d_out, int out_size, void* d_ws, size_t ws_size,
                              hipStream_t stream) {
  (void)in_sizes; (void)n_in; (void)out_size; (void)ws_size;
  const float* x   = (const float*)d_in[0];
  const float* Wh  = (const float*)d_in[1];
  const float* Wz  = (const float*)d_in[2];
  const float* Uh  = (const float*)d_in[3];
  const float* Uz  = (const float*)d_in[4];
  const float* gwh = (const float*)d_in[5];
  const float* bwh = (const float*)d_in[6];
  const float* gwz = (const float*)d_in[7];
  const float* bwz = (const float*)d_in[8];

  char* ws = (char*)d_ws;
  float*              sums  = (float*)(ws + 0);                  // 8192 B
  float*              sumsq = (float*)(ws + 8192);               // 8192 B
  unsigned long long* hrec  = (unsigned long long*)(ws + 16384); // 262144 B
  unsigned int*       ctrl  = (unsigned int*)(ws + 278528);      // 512 B
  unsigned short*     Wb    = (unsigned short*)(ws + 279040);    // 2 MiB

  // zero stats + records + ctrl every call (graph-replay safe; tag=0 == valid h0=0)
  hipMemsetAsync(d_ws, 0, 279040, stream);
  k_convw<<<1024, 256, 0, stream>>>(Wh, Wz, Wb);
  // P (bf16) lives in d_out; scan overwrites it with f32 output in provably-ordered fashion
  k_gemm<<<8000, 256, 0, stream>>>(x, Wb, (unsigned short*)d_out, sums, sumsq);
  k_scan<<<NW, 256, 0, stream>>>(Uh, Uz, gwh, bwh, gwz, bwz,
                                 (const unsigned short*)d_out, sums, sumsq,
                                 hrec, ctrl, (float*)d_out);
}